// Round 1
// baseline (1161.271 us; speedup 1.0000x reference)
//
#include <hip/hip_runtime.h>

// Problem constants (from reference)
constexpr int B_ = 16;
constexpr int NV = 20000;      // N vertices
constexpr int KN = 16;         // K neighbors
constexpr int LAT = 256;       // LATENT
constexpr int HID = 1024;      // HIDDEN
constexpr int N3 = 60000;      // N*3
constexpr float INV_NK = 1.0f / (20000.0f * 16.0f);

// Workspace layout (floats)
constexpr int H_OFF = 0;                       // h        [16][1024]
constexpr int RECON_OFF = B_ * HID;            // recon    [16][60000]
constexpr int GRECON_OFF = RECON_OFF + B_ * N3;// g_recon  [16][60000]
constexpr int GH_OFF = GRECON_OFF + B_ * N3;   // g_h      [16][1024]

__device__ __forceinline__ void atomAddF(float* p, float v) {
  unsafeAtomicAdd(p, v);   // hardware global_atomic_add_f32 on gfx950
}

// ---------------- h = relu(code @ W1 + b1) ----------------
__global__ __launch_bounds__(256) void k_mlp1(
    const float* __restrict__ code, const float* __restrict__ W1,
    const float* __restrict__ b1, float* __restrict__ h) {
  int t = blockIdx.x * 256 + threadIdx.x;     // 0..16383
  int b = t >> 10, hd = t & 1023;
  const float* c = code + b * LAT;
  float acc = b1[hd];
  #pragma unroll 4
  for (int l = 0; l < LAT; ++l) acc += c[l] * W1[l * HID + hd];
  h[t] = fmaxf(acc, 0.0f);
}

// ---------------- recon = h @ W2 + b2 (hd split in 2, atomic accumulate) ----------------
__global__ __launch_bounds__(256) void k_mlp2(
    const float* __restrict__ h, const float* __restrict__ W2,
    const float* __restrict__ b2, float* __restrict__ recon) {
  __shared__ float hs[16][128];
  int j = blockIdx.x * 256 + threadIdx.x;
  int hd_base = blockIdx.y * 512;
  bool valid = (j < N3);
  float acc[16];
  #pragma unroll
  for (int b = 0; b < 16; ++b) acc[b] = 0.0f;

  for (int c0 = 0; c0 < 512; c0 += 128) {
    __syncthreads();
    #pragma unroll
    for (int r = 0; r < 8; ++r) {           // stage h[0:16][chunk of 128]
      int idx = r * 256 + threadIdx.x;
      int bb = idx >> 7, cc = idx & 127;
      hs[bb][cc] = h[bb * HID + hd_base + c0 + cc];
    }
    __syncthreads();
    if (valid) {
      const float* wp = W2 + (hd_base + c0) * N3 + j;
      #pragma unroll 8
      for (int i = 0; i < 128; ++i) {
        float w = wp[i * N3];
        #pragma unroll
        for (int b = 0; b < 16; ++b) acc[b] += hs[b][i] * w;
      }
    }
  }
  if (valid) {
    float bias = (blockIdx.y == 0) ? b2[j] : 0.0f;
    #pragma unroll
    for (int b = 0; b < 16; ++b) atomAddF(&recon[b * N3 + j], acc[b] + bias);
  }
}

// ---------------- fused ARAP: S, rotation, energy, g_recon scatter ----------------
__global__ __launch_bounds__(256, 2) void k_edge(
    const float* __restrict__ xyz, const float* __restrict__ recon,
    const float* __restrict__ wmat, const float* __restrict__ area,
    const int* __restrict__ nbrs, const int* __restrict__ nnbr,
    float* __restrict__ grecon, float* __restrict__ energy) {
  __shared__ float red[256];
  const int tid = threadIdx.x;
  const int n = blockIdx.x * 256 + tid;
  const int b = blockIdx.y;
  float esum = 0.0f;
  if (n < NV) {
    const int nn = nnbr[n];
    const float ar = area[n];
    const float* xb = xyz + b * (NV * 3);
    const float* qb = recon + b * N3;
    const float x0 = xb[n * 3 + 0], x1 = xb[n * 3 + 1], x2 = xb[n * 3 + 2];
    const float q0 = qb[n * 3 + 0], q1 = qb[n * 3 + 1], q2 = qb[n * 3 + 2];

    float dX[KN], dY[KN], dZ[KN], eX[KN], eY[KN], eZ[KN], wk[KN];
    int mk[KN];
    float S00=0,S01=0,S02=0,S10=0,S11=0,S12=0,S20=0,S21=0,S22=0;
    #pragma unroll
    for (int k = 0; k < KN; ++k) {
      float w=0, dx=0, dy=0, dz=0, ex=0, ey=0, ez=0; int m = 0;
      if (k < nn) {
        m = nbrs[n * KN + k];
        w = wmat[n * KN + k];
        dx = x0 - xb[m * 3 + 0]; dy = x1 - xb[m * 3 + 1]; dz = x2 - xb[m * 3 + 2];
        ex = q0 - qb[m * 3 + 0]; ey = q1 - qb[m * 3 + 1]; ez = q2 - qb[m * 3 + 2];
      }
      mk[k] = m; wk[k] = w;
      dX[k]=dx; dY[k]=dy; dZ[k]=dz; eX[k]=ex; eY[k]=ey; eZ[k]=ez;
      S00 += w*dx*ex; S01 += w*dx*ey; S02 += w*dx*ez;
      S10 += w*dy*ex; S11 += w*dy*ey; S12 += w*dy*ez;
      S20 += w*dz*ex; S21 += w*dz*ey; S22 += w*dz*ez;
    }

    // A = S^T S (symmetric), Jacobi eigendecomposition -> V columns
    float A00 = S00*S00 + S10*S10 + S20*S20;
    float A01 = S00*S01 + S10*S11 + S20*S21;
    float A02 = S00*S02 + S10*S12 + S20*S22;
    float A11 = S01*S01 + S11*S11 + S21*S21;
    float A12 = S01*S02 + S11*S12 + S21*S22;
    float A22 = S02*S02 + S12*S12 + S22*S22;
    float V00=1,V01=0,V02=0, V10=0,V11=1,V12=0, V20=0,V21=0,V22=1;

    auto rot = [&](float& app, float& aqq, float& apq, float& arp, float& arq,
                   float& vp0, float& vp1, float& vp2,
                   float& vq0, float& vq1, float& vq2) {
      float a = apq;
      if (fabsf(a) > 1e-37f) {
        float tau = (aqq - app) * 0.5f / a;
        float t = copysignf(1.0f, tau) / (fabsf(tau) + sqrtf(1.0f + tau * tau));
        float c = rsqrtf(1.0f + t * t);
        float s = t * c;
        float napp = c*c*app - 2.0f*s*c*a + s*s*aqq;
        float naqq = s*s*app + 2.0f*s*c*a + c*c*aqq;
        app = napp; aqq = naqq; apq = 0.0f;
        float rp = arp, rq = arq;
        arp = c*rp - s*rq; arq = s*rp + c*rq;
        float t0, t1;
        t0=vp0; t1=vq0; vp0 = c*t0 - s*t1; vq0 = s*t0 + c*t1;
        t0=vp1; t1=vq1; vp1 = c*t0 - s*t1; vq1 = s*t0 + c*t1;
        t0=vp2; t1=vq2; vp2 = c*t0 - s*t1; vq2 = s*t0 + c*t1;
      }
    };
    #pragma unroll
    for (int sweep = 0; sweep < 6; ++sweep) {
      rot(A00,A11,A01, A02,A12, V00,V10,V20, V01,V11,V21); // (p,q)=(0,1)
      rot(A00,A22,A02, A01,A12, V00,V10,V20, V02,V12,V22); // (p,q)=(0,2)
      rot(A11,A22,A12, A01,A02, V01,V11,V21, V02,V12,V22); // (p,q)=(1,2)
    }
    // sort eigenpairs descending (column swaps)
    auto sw = [](float& a, float& c) { float t = a; a = c; c = t; };
    if (A00 < A11) { sw(A00,A11); sw(V00,V01); sw(V10,V11); sw(V20,V21); }
    if (A00 < A22) { sw(A00,A22); sw(V00,V02); sw(V10,V12); sw(V20,V22); }
    if (A11 < A22) { sw(A11,A22); sw(V01,V02); sw(V11,V12); sw(V21,V22); }

    float v1x=V00, v1y=V10, v1z=V20;
    float v2x=V01, v2y=V11, v2z=V21;

    // u1 = normalize(S v1); u2 = normalize(S v2 orthogonalized vs u1)
    float u1x = S00*v1x + S01*v1y + S02*v1z;
    float u1y = S10*v1x + S11*v1y + S12*v1z;
    float u1z = S20*v1x + S21*v1y + S22*v1z;
    float s1sq = u1x*u1x + u1y*u1y + u1z*u1z;
    if (s1sq > 1e-30f) { float r = rsqrtf(s1sq); u1x*=r; u1y*=r; u1z*=r; }
    else { u1x = 1.0f; u1y = 0.0f; u1z = 0.0f; }

    float u2x = S00*v2x + S01*v2y + S02*v2z;
    float u2y = S10*v2x + S11*v2y + S12*v2z;
    float u2z = S20*v2x + S21*v2y + S22*v2z;
    float pr = u2x*u1x + u2y*u1y + u2z*u1z;
    u2x -= pr*u1x; u2y -= pr*u1y; u2z -= pr*u1z;
    float s2sq = u2x*u2x + u2y*u2y + u2z*u2z;
    if (s2sq > 1e-12f * s1sq + 1e-30f) {
      float r = rsqrtf(s2sq); u2x*=r; u2y*=r; u2z*=r;
    } else {
      // rank-deficient: any unit vector perpendicular to u1 (only multiplies wm=0 terms)
      float ex_ = (fabsf(u1x) < 0.9f) ? 1.0f : 0.0f;
      float ey_ = 1.0f - ex_;
      float pp = ex_*u1x + ey_*u1y;
      u2x = ex_ - pp*u1x; u2y = ey_ - pp*u1y; u2z = -pp*u1z;
      float r = rsqrtf(u2x*u2x + u2y*u2y + u2z*u2z);
      u2x*=r; u2y*=r; u2z*=r;
    }
    // right-handed completion reproduces the reference's det-sign flip exactly
    float u3x = u1y*u2z - u1z*u2y, u3y = u1z*u2x - u1x*u2z, u3z = u1x*u2y - u1y*u2x;
    float v3x = v1y*v2z - v1z*v2y, v3y = v1z*v2x - v1x*v2z, v3z = v1x*v2y - v1y*v2x;

    float R00 = v1x*u1x + v2x*u2x + v3x*u3x;
    float R01 = v1x*u1y + v2x*u2y + v3x*u3y;
    float R02 = v1x*u1z + v2x*u2z + v3x*u3z;
    float R10 = v1y*u1x + v2y*u2x + v3y*u3x;
    float R11 = v1y*u1y + v2y*u2y + v3y*u3y;
    float R12 = v1y*u1z + v2y*u2z + v3y*u3z;
    float R20 = v1z*u1x + v2z*u2x + v3z*u3x;
    float R21 = v1z*u1y + v2z*u2y + v3z*u3y;
    float R22 = v1z*u1z + v2z*u2z + v3z*u3z;

    const float gf = 2.0f * ar * INV_NK;
    float gox = 0, goy = 0, goz = 0;
    #pragma unroll
    for (int k = 0; k < KN; ++k) {
      float w = wk[k];
      if (w > 0.0f) {
        float dx = dX[k], dy = dY[k], dz = dZ[k];
        float rx = eX[k] - (R00*dx + R01*dy + R02*dz);
        float ry = eY[k] - (R10*dx + R11*dy + R12*dz);
        float rz = eZ[k] - (R20*dx + R21*dy + R22*dz);
        esum += w * (rx*rx + ry*ry + rz*rz);
        float gc = gf * w;
        gox += gc*rx; goy += gc*ry; goz += gc*rz;
        float* gp = grecon + b * N3 + mk[k] * 3;
        atomAddF(gp + 0, -gc*rx); atomAddF(gp + 1, -gc*ry); atomAddF(gp + 2, -gc*rz);
      }
    }
    esum *= ar;
    float* gq = grecon + b * N3 + n * 3;
    atomAddF(gq + 0, gox); atomAddF(gq + 1, goy); atomAddF(gq + 2, goz);
  }
  // block-reduce energy
  red[tid] = esum;
  __syncthreads();
  #pragma unroll
  for (int s = 128; s > 0; s >>= 1) {
    if (tid < s) red[tid] += red[tid + s];
    __syncthreads();
  }
  if (tid == 0) atomAddF(&energy[b], red[0] * INV_NK);
}

// ---------------- g_h = g_recon @ W2^T (LDS-transposed tiles) ----------------
__global__ __launch_bounds__(256) void k_mlp2_bwd(
    const float* __restrict__ gr, const float* __restrict__ W2,
    float* __restrict__ gh) {
  __shared__ float tw[128 * 65];   // 128 hd x 64 j, padded stride 65 (conflict-free)
  __shared__ float gt[16 * 64];    // 16 b x 64 j
  const int tid = threadIdx.x;
  const int lane = tid & 63;
  const int wv = tid >> 6;         // 0..3
  const int hd0 = blockIdx.y * 128;
  const int hl = tid & 127;        // hd_local for compute
  const int bg = tid >> 7;         // 0 or 1 -> b in [bg*8, bg*8+8)
  float acc[8];
  #pragma unroll
  for (int i = 0; i < 8; ++i) acc[i] = 0.0f;

  for (int tt = 0; tt < 8; ++tt) {
    int j0 = blockIdx.x * 512 + tt * 64;
    if (j0 >= N3) break;           // uniform (blockIdx-based)
    __syncthreads();
    int j = j0 + lane;
    bool jv = (j < N3);
    #pragma unroll
    for (int rr = 0; rr < 32; ++rr) {          // load W2 tile 128x64 coalesced
      int row = rr * 4 + wv;
      tw[row * 65 + lane] = jv ? W2[(hd0 + row) * N3 + j] : 0.0f;
    }
    #pragma unroll
    for (int bb = 0; bb < 4; ++bb) {           // load g tile 16x64
      int b = bb * 4 + wv;
      gt[b * 64 + lane] = jv ? gr[b * N3 + j] : 0.0f;
    }
    __syncthreads();
    #pragma unroll 4
    for (int jj = 0; jj < 64; ++jj) {
      float w = tw[hl * 65 + jj];
      #pragma unroll
      for (int ib = 0; ib < 8; ++ib)
        acc[ib] += w * gt[(bg * 8 + ib) * 64 + jj];
    }
  }
  #pragma unroll
  for (int ib = 0; ib < 8; ++ib)
    atomAddF(&gh[(bg * 8 + ib) * HID + hd0 + hl], acc[ib]);
}

// ---------------- g_code = (g_h * relu') @ W1^T ----------------
__global__ __launch_bounds__(256) void k_mlp1_bwd(
    const float* __restrict__ gh, const float* __restrict__ h,
    const float* __restrict__ W1, float* __restrict__ gcode) {
  __shared__ float gm[HID];
  const int b = blockIdx.x, l = threadIdx.x;
  for (int i = l; i < HID; i += 256) {
    float g = gh[b * HID + i];
    gm[i] = (h[b * HID + i] > 0.0f) ? g : 0.0f;
  }
  __syncthreads();
  float acc = 0.0f;
  #pragma unroll 8
  for (int hd = 0; hd < HID; ++hd) acc += gm[hd] * W1[l * HID + hd];
  gcode[b * LAT + l] = acc;
}

extern "C" void kernel_launch(void* const* d_in, const int* in_sizes, int n_in,
                              void* d_out, int out_size, void* d_ws, size_t ws_size,
                              hipStream_t stream) {
  const float* code = (const float*)d_in[0];
  const float* W1   = (const float*)d_in[1];
  const float* b1   = (const float*)d_in[2];
  const float* W2   = (const float*)d_in[3];
  const float* b2   = (const float*)d_in[4];
  const float* xyz  = (const float*)d_in[5];
  const float* wmat = (const float*)d_in[6];
  const float* area = (const float*)d_in[7];
  const int* nbrs   = (const int*)d_in[8];
  const int* nnbr   = (const int*)d_in[9];

  float* out = (float*)d_out;           // [16] meanEnergy, [16*256] code_grad
  float* ws = (float*)d_ws;
  float* h      = ws + H_OFF;
  float* recon  = ws + RECON_OFF;
  float* grecon = ws + GRECON_OFF;
  float* gh     = ws + GH_OFF;

  // zero accumulators: recon, g_recon, g_h (contiguous) + energy slots
  hipMemsetAsync(recon, 0, (size_t)(2 * B_ * N3 + B_ * HID) * sizeof(float), stream);
  hipMemsetAsync(out, 0, B_ * sizeof(float), stream);

  k_mlp1<<<dim3(64), dim3(256), 0, stream>>>(code, W1, b1, h);
  k_mlp2<<<dim3((N3 + 255) / 256, 2), dim3(256), 0, stream>>>(h, W2, b2, recon);
  k_edge<<<dim3((NV + 255) / 256, B_), dim3(256), 0, stream>>>(
      xyz, recon, wmat, area, nbrs, nnbr, grecon, out);
  k_mlp2_bwd<<<dim3(118, 8), dim3(256), 0, stream>>>(grecon, W2, gh);
  k_mlp1_bwd<<<dim3(B_), dim3(256), 0, stream>>>(gh, h, W1, out + B_);
}

// Round 2
// 966.403 us; speedup vs baseline: 1.2016x; 1.2016x over previous
//
#include <hip/hip_runtime.h>

// Problem constants (from reference)
constexpr int B_ = 16;
constexpr int NV = 20000;      // N vertices
constexpr int KN = 16;         // K neighbors
constexpr int LAT = 256;       // LATENT
constexpr int HID = 1024;      // HIDDEN
constexpr int N3 = 60000;      // N*3
constexpr int RCAP = 64;       // reverse-adjacency capacity (Poisson(8.5) tail ~0)
constexpr float INV_NK = 1.0f / (20000.0f * 16.0f);

// Workspace layout (float units)
constexpr size_t H_OFF      = 0;                          // h        [16][1024]
constexpr size_t RECON_OFF  = H_OFF + B_ * HID;           // recon    [16][60000]
constexpr size_t GRECON_OFF = RECON_OFF + B_ * N3;        // g_recon  [16][60000]
constexpr size_t GH_OFF     = GRECON_OFF + B_ * N3;       // g_h      [16][1024]
constexpr size_t RBUF_OFF   = GH_OFF + B_ * HID;          // R+ownG   [20000][16][12]
constexpr size_t RCOUNT_OFF = RBUF_OFF + (size_t)NV * 16 * 12;  // int [20000]
constexpr size_t RLIST_OFF  = RCOUNT_OFF + NV;            // int     [20000][64]

__device__ __forceinline__ void atomAddF(float* p, float v) {
  unsafeAtomicAdd(p, v);   // hardware global_atomic_add_f32 on gfx950
}

// ---------------- h = relu(code @ W1 + b1) ----------------
__global__ __launch_bounds__(256) void k_mlp1(
    const float* __restrict__ code, const float* __restrict__ W1,
    const float* __restrict__ b1, float* __restrict__ h) {
  int t = blockIdx.x * 256 + threadIdx.x;     // 0..16383
  int b = t >> 10, hd = t & 1023;
  const float* c = code + b * LAT;
  float acc = b1[hd];
  #pragma unroll 4
  for (int l = 0; l < LAT; ++l) acc += c[l] * W1[l * HID + hd];
  h[t] = fmaxf(acc, 0.0f);
}

// ---------------- recon = h @ W2 + b2 (hd split in 2, atomic accumulate) ----------------
__global__ __launch_bounds__(256) void k_mlp2(
    const float* __restrict__ h, const float* __restrict__ W2,
    const float* __restrict__ b2, float* __restrict__ recon) {
  __shared__ float hs[16][128];
  int j = blockIdx.x * 256 + threadIdx.x;
  int hd_base = blockIdx.y * 512;
  bool valid = (j < N3);
  float acc[16];
  #pragma unroll
  for (int b = 0; b < 16; ++b) acc[b] = 0.0f;

  for (int c0 = 0; c0 < 512; c0 += 128) {
    __syncthreads();
    #pragma unroll
    for (int r = 0; r < 8; ++r) {           // stage h[0:16][chunk of 128]
      int idx = r * 256 + threadIdx.x;
      int bb = idx >> 7, cc = idx & 127;
      hs[bb][cc] = h[bb * HID + hd_base + c0 + cc];
    }
    __syncthreads();
    if (valid) {
      const float* wp = W2 + (size_t)(hd_base + c0) * N3 + j;
      #pragma unroll 8
      for (int i = 0; i < 128; ++i) {
        float w = wp[(size_t)i * N3];
        #pragma unroll
        for (int b = 0; b < 16; ++b) acc[b] += hs[b][i] * w;
      }
    }
  }
  if (valid) {
    float bias = (blockIdx.y == 0) ? b2[j] : 0.0f;
    #pragma unroll
    for (int b = 0; b < 16; ++b) atomAddF(&recon[b * N3 + j], acc[b] + bias);
  }
}

// ---------------- reverse adjacency fill ----------------
__global__ __launch_bounds__(256) void k_fill(
    const int* __restrict__ nbrs, const int* __restrict__ nnbr,
    int* __restrict__ rcount, int* __restrict__ rlist) {
  int e = blockIdx.x * 256 + threadIdx.x;   // 0..319999
  int n = e >> 4, k = e & 15;
  if (k < nnbr[n]) {
    int v = nbrs[e];
    int slot = atomicAdd(&rcount[v], 1);
    if (slot < RCAP) rlist[v * RCAP + slot] = e;
  }
}

// ---------------- per-vertex: S, Jacobi->R, energy, own-grad; no scatter ----------------
// block = 16 vertices x 16 batches (b = tid&15, lane-fastest)
__global__ __launch_bounds__(256) void k_rot(
    const float* __restrict__ xyz, const float* __restrict__ recon,
    const float* __restrict__ wmat, const float* __restrict__ area,
    const int* __restrict__ nbrs, const int* __restrict__ nnbr,
    float* __restrict__ Rbuf, float* __restrict__ energy) {
  __shared__ float red[64];
  const int tid = threadIdx.x;
  const int b = tid & 15, nl = tid >> 4;
  const int n = blockIdx.x * 16 + nl;       // grid 1250 -> exactly 20000
  const float* xb = xyz + b * N3;
  const float* qb = recon + b * N3;
  const int nn = nnbr[n];
  const float ar = area[n];
  const float x0 = xb[n*3+0], x1 = xb[n*3+1], x2 = xb[n*3+2];
  const float q0 = qb[n*3+0], q1 = qb[n*3+1], q2 = qb[n*3+2];

  float S00=0,S01=0,S02=0,S10=0,S11=0,S12=0,S20=0,S21=0,S22=0;
  for (int k = 0; k < nn; ++k) {
    int m = nbrs[n * KN + k];               // broadcast across 16 b-lanes
    float w = wmat[n * KN + k];
    float dx = x0 - xb[m*3+0], dy = x1 - xb[m*3+1], dz = x2 - xb[m*3+2];
    float ex = q0 - qb[m*3+0], ey = q1 - qb[m*3+1], ez = q2 - qb[m*3+2];
    S00 += w*dx*ex; S01 += w*dx*ey; S02 += w*dx*ez;
    S10 += w*dy*ex; S11 += w*dy*ey; S12 += w*dy*ez;
    S20 += w*dz*ex; S21 += w*dz*ey; S22 += w*dz*ez;
  }

  // A = S^T S, Jacobi eigendecomposition -> V (validated round 1)
  float A00 = S00*S00 + S10*S10 + S20*S20;
  float A01 = S00*S01 + S10*S11 + S20*S21;
  float A02 = S00*S02 + S10*S12 + S20*S22;
  float A11 = S01*S01 + S11*S11 + S21*S21;
  float A12 = S01*S02 + S11*S12 + S21*S22;
  float A22 = S02*S02 + S12*S12 + S22*S22;
  float V00=1,V01=0,V02=0, V10=0,V11=1,V12=0, V20=0,V21=0,V22=1;

  auto rot = [&](float& app, float& aqq, float& apq, float& arp, float& arq,
                 float& vp0, float& vp1, float& vp2,
                 float& vq0, float& vq1, float& vq2) {
    float a = apq;
    if (fabsf(a) > 1e-37f) {
      float tau = (aqq - app) * 0.5f / a;
      float t = copysignf(1.0f, tau) / (fabsf(tau) + sqrtf(1.0f + tau * tau));
      float c = rsqrtf(1.0f + t * t);
      float s = t * c;
      float napp = c*c*app - 2.0f*s*c*a + s*s*aqq;
      float naqq = s*s*app + 2.0f*s*c*a + c*c*aqq;
      app = napp; aqq = naqq; apq = 0.0f;
      float rp = arp, rq = arq;
      arp = c*rp - s*rq; arq = s*rp + c*rq;
      float t0, t1;
      t0=vp0; t1=vq0; vp0 = c*t0 - s*t1; vq0 = s*t0 + c*t1;
      t0=vp1; t1=vq1; vp1 = c*t0 - s*t1; vq1 = s*t0 + c*t1;
      t0=vp2; t1=vq2; vp2 = c*t0 - s*t1; vq2 = s*t0 + c*t1;
    }
  };
  #pragma unroll
  for (int sweep = 0; sweep < 6; ++sweep) {
    rot(A00,A11,A01, A02,A12, V00,V10,V20, V01,V11,V21);
    rot(A00,A22,A02, A01,A12, V00,V10,V20, V02,V12,V22);
    rot(A11,A22,A12, A01,A02, V01,V11,V21, V02,V12,V22);
  }
  auto sw = [](float& a, float& c) { float t = a; a = c; c = t; };
  if (A00 < A11) { sw(A00,A11); sw(V00,V01); sw(V10,V11); sw(V20,V21); }
  if (A00 < A22) { sw(A00,A22); sw(V00,V02); sw(V10,V12); sw(V20,V22); }
  if (A11 < A22) { sw(A11,A22); sw(V01,V02); sw(V11,V12); sw(V21,V22); }

  float v1x=V00, v1y=V10, v1z=V20;
  float v2x=V01, v2y=V11, v2z=V21;

  float u1x = S00*v1x + S01*v1y + S02*v1z;
  float u1y = S10*v1x + S11*v1y + S12*v1z;
  float u1z = S20*v1x + S21*v1y + S22*v1z;
  float s1sq = u1x*u1x + u1y*u1y + u1z*u1z;
  if (s1sq > 1e-30f) { float r = rsqrtf(s1sq); u1x*=r; u1y*=r; u1z*=r; }
  else { u1x = 1.0f; u1y = 0.0f; u1z = 0.0f; }

  float u2x = S00*v2x + S01*v2y + S02*v2z;
  float u2y = S10*v2x + S11*v2y + S12*v2z;
  float u2z = S20*v2x + S21*v2y + S22*v2z;
  float pr = u2x*u1x + u2y*u1y + u2z*u1z;
  u2x -= pr*u1x; u2y -= pr*u1y; u2z -= pr*u1z;
  float s2sq = u2x*u2x + u2y*u2y + u2z*u2z;
  if (s2sq > 1e-12f * s1sq + 1e-30f) {
    float r = rsqrtf(s2sq); u2x*=r; u2y*=r; u2z*=r;
  } else {
    float ex_ = (fabsf(u1x) < 0.9f) ? 1.0f : 0.0f;
    float ey_ = 1.0f - ex_;
    float pp = ex_*u1x + ey_*u1y;
    u2x = ex_ - pp*u1x; u2y = ey_ - pp*u1y; u2z = -pp*u1z;
    float r = rsqrtf(u2x*u2x + u2y*u2y + u2z*u2z);
    u2x*=r; u2y*=r; u2z*=r;
  }
  float u3x = u1y*u2z - u1z*u2y, u3y = u1z*u2x - u1x*u2z, u3z = u1x*u2y - u1y*u2x;
  float v3x = v1y*v2z - v1z*v2y, v3y = v1z*v2x - v1x*v2z, v3z = v1x*v2y - v1y*v2x;

  float R00 = v1x*u1x + v2x*u2x + v3x*u3x;
  float R01 = v1x*u1y + v2x*u2y + v3x*u3y;
  float R02 = v1x*u1z + v2x*u2z + v3x*u3z;
  float R10 = v1y*u1x + v2y*u2x + v3y*u3x;
  float R11 = v1y*u1y + v2y*u2y + v3y*u3y;
  float R12 = v1y*u1z + v2y*u2z + v3y*u3z;
  float R20 = v1z*u1x + v2z*u2x + v3z*u3x;
  float R21 = v1z*u1y + v2z*u2y + v3z*u3y;
  float R22 = v1z*u1z + v2z*u2z + v3z*u3z;

  // pass 2: residuals -> energy + own-vertex gradient (gathers are L1/L2-hot)
  float esum = 0, go0 = 0, go1 = 0, go2 = 0;
  const float gf = 2.0f * ar * INV_NK;
  for (int k = 0; k < nn; ++k) {
    int m = nbrs[n * KN + k];
    float w = wmat[n * KN + k];
    float dx = x0 - xb[m*3+0], dy = x1 - xb[m*3+1], dz = x2 - xb[m*3+2];
    float ex = q0 - qb[m*3+0], ey = q1 - qb[m*3+1], ez = q2 - qb[m*3+2];
    float rx = ex - (R00*dx + R01*dy + R02*dz);
    float ry = ey - (R10*dx + R11*dy + R12*dz);
    float rz = ez - (R20*dx + R21*dy + R22*dz);
    esum += w * (rx*rx + ry*ry + rz*rz);
    float gc = gf * w;
    go0 += gc*rx; go1 += gc*ry; go2 += gc*rz;
  }
  esum *= ar * INV_NK;

  // coalesced 48B store: R (9) + own grad (3)
  float4* rp = (float4*)(Rbuf + (size_t)(n * 16 + b) * 12);
  rp[0] = make_float4(R00, R01, R02, R10);
  rp[1] = make_float4(R11, R12, R20, R21);
  rp[2] = make_float4(R22, go0, go1, go2);

  // energy reduce: wave (4n x 16b) -> per-b lanes 0..15 -> LDS -> one atomic per b
  esum += __shfl_down(esum, 32);
  esum += __shfl_down(esum, 16);
  int wave = tid >> 6, lane = tid & 63;
  if (lane < 16) red[wave * 16 + lane] = esum;
  __syncthreads();
  if (tid < 16) atomAddF(&energy[tid], red[tid] + red[16 + tid] + red[32 + tid] + red[48 + tid]);
}

// ---------------- gather incoming edge grads, write final g_recon (no atomics) ----------------
__global__ __launch_bounds__(256) void k_scatter(
    const float* __restrict__ xyz, const float* __restrict__ recon,
    const float* __restrict__ wmat, const float* __restrict__ area,
    const float* __restrict__ Rbuf, const int* __restrict__ rcount,
    const int* __restrict__ rlist, float* __restrict__ grecon) {
  int t = blockIdx.x * 256 + threadIdx.x;   // grid 1250 -> 320000 = 20000*16
  int v = t >> 4, b = t & 15;
  const float* xb = xyz + b * N3;
  const float* qb = recon + b * N3;
  const float xv0 = xb[v*3+0], xv1 = xb[v*3+1], xv2 = xb[v*3+2];
  const float qv0 = qb[v*3+0], qv1 = qb[v*3+1], qv2 = qb[v*3+2];
  float g0 = 0, g1 = 0, g2 = 0;
  int deg = min(rcount[v], RCAP);
  for (int i = 0; i < deg; ++i) {
    int e = rlist[v * RCAP + i];            // broadcast across 16 b-lanes
    int n = e >> 4;
    float gc = 2.0f * INV_NK * area[n] * wmat[e];
    const float4* rp = (const float4*)(Rbuf + (size_t)(n * 16 + b) * 12);
    float4 ra = rp[0], rb = rp[1], rc = rp[2];   // 16 lanes read 768B contiguous
    float dx = xb[n*3+0] - xv0, dy = xb[n*3+1] - xv1, dz = xb[n*3+2] - xv2;
    float ex = qb[n*3+0] - qv0, ey = qb[n*3+1] - qv1, ez = qb[n*3+2] - qv2;
    float rx = ex - (ra.x*dx + ra.y*dy + ra.z*dz);
    float ry = ey - (ra.w*dx + rb.x*dy + rb.y*dz);
    float rz = ez - (rb.z*dx + rb.w*dy + rc.x*dz);
    g0 -= gc*rx; g1 -= gc*ry; g2 -= gc*rz;
  }
  const float4* op = (const float4*)(Rbuf + (size_t)(v * 16 + b) * 12);
  float4 oc = op[2];                        // (R22, go0, go1, go2)
  g0 += oc.y; g1 += oc.z; g2 += oc.w;
  float* gq = grecon + (size_t)b * N3 + v * 3;
  gq[0] = g0; gq[1] = g1; gq[2] = g2;
}

// ---------------- g_h = g_recon @ W2^T (LDS-transposed tiles) ----------------
__global__ __launch_bounds__(256) void k_mlp2_bwd(
    const float* __restrict__ gr, const float* __restrict__ W2,
    float* __restrict__ gh) {
  __shared__ float tw[128 * 65];   // 128 hd x 64 j, padded stride 65
  __shared__ float gt[16 * 64];    // 16 b x 64 j
  const int tid = threadIdx.x;
  const int lane = tid & 63;
  const int wv = tid >> 6;
  const int hd0 = blockIdx.y * 128;
  const int hl = tid & 127;
  const int bg = tid >> 7;
  float acc[8];
  #pragma unroll
  for (int i = 0; i < 8; ++i) acc[i] = 0.0f;

  for (int tt = 0; tt < 8; ++tt) {
    int j0 = blockIdx.x * 512 + tt * 64;
    if (j0 >= N3) break;
    __syncthreads();
    int j = j0 + lane;
    bool jv = (j < N3);
    #pragma unroll
    for (int rr = 0; rr < 32; ++rr) {
      int row = rr * 4 + wv;
      tw[row * 65 + lane] = jv ? W2[(size_t)(hd0 + row) * N3 + j] : 0.0f;
    }
    #pragma unroll
    for (int bb = 0; bb < 4; ++bb) {
      int b = bb * 4 + wv;
      gt[b * 64 + lane] = jv ? gr[(size_t)b * N3 + j] : 0.0f;
    }
    __syncthreads();
    #pragma unroll 4
    for (int jj = 0; jj < 64; ++jj) {
      float w = tw[hl * 65 + jj];
      #pragma unroll
      for (int ib = 0; ib < 8; ++ib)
        acc[ib] += w * gt[(bg * 8 + ib) * 64 + jj];
    }
  }
  #pragma unroll
  for (int ib = 0; ib < 8; ++ib)
    atomAddF(&gh[(bg * 8 + ib) * HID + hd0 + hl], acc[ib]);
}

// ---------------- g_code = (g_h * relu') @ W1^T ----------------
__global__ __launch_bounds__(256) void k_mlp1_bwd(
    const float* __restrict__ gh, const float* __restrict__ h,
    const float* __restrict__ W1, float* __restrict__ gcode) {
  __shared__ float gm[128];
  const int b = blockIdx.x;
  const int hd0 = blockIdx.y * 128;
  const int l = threadIdx.x;
  if (l < 128) {
    float g = gh[b * HID + hd0 + l];
    gm[l] = (h[b * HID + hd0 + l] > 0.0f) ? g : 0.0f;
  }
  __syncthreads();
  const float4* wp = (const float4*)(W1 + (size_t)l * HID + hd0);
  float acc = 0.0f;
  #pragma unroll
  for (int i = 0; i < 32; ++i) {
    float4 w4 = wp[i];
    acc += w4.x * gm[i*4+0] + w4.y * gm[i*4+1] + w4.z * gm[i*4+2] + w4.w * gm[i*4+3];
  }
  atomAddF(&gcode[b * LAT + l], acc);
}

extern "C" void kernel_launch(void* const* d_in, const int* in_sizes, int n_in,
                              void* d_out, int out_size, void* d_ws, size_t ws_size,
                              hipStream_t stream) {
  const float* code = (const float*)d_in[0];
  const float* W1   = (const float*)d_in[1];
  const float* b1   = (const float*)d_in[2];
  const float* W2   = (const float*)d_in[3];
  const float* b2   = (const float*)d_in[4];
  const float* xyz  = (const float*)d_in[5];
  const float* wmat = (const float*)d_in[6];
  const float* area = (const float*)d_in[7];
  const int* nbrs   = (const int*)d_in[8];
  const int* nnbr   = (const int*)d_in[9];

  float* out = (float*)d_out;           // [16] meanEnergy, [16*256] code_grad
  float* ws = (float*)d_ws;
  float* h      = ws + H_OFF;
  float* recon  = ws + RECON_OFF;
  float* grecon = ws + GRECON_OFF;
  float* gh     = ws + GH_OFF;
  float* Rbuf   = ws + RBUF_OFF;
  int*   rcount = (int*)(ws + RCOUNT_OFF);
  int*   rlist  = (int*)(ws + RLIST_OFF);

  // zero only what accumulates via atomics: recon (k_mlp2), gh (k_mlp2_bwd),
  // rcount (k_fill), out (energy + gcode atomics). grecon is written exclusively.
  hipMemsetAsync(recon, 0, (size_t)B_ * N3 * sizeof(float), stream);
  hipMemsetAsync(gh, 0, (size_t)B_ * HID * sizeof(float), stream);
  hipMemsetAsync(rcount, 0, (size_t)NV * sizeof(int), stream);
  hipMemsetAsync(out, 0, (size_t)(B_ + B_ * LAT) * sizeof(float), stream);

  k_fill<<<dim3(NV * KN / 256), dim3(256), 0, stream>>>(nbrs, nnbr, rcount, rlist);
  k_mlp1<<<dim3(64), dim3(256), 0, stream>>>(code, W1, b1, h);
  k_mlp2<<<dim3((N3 + 255) / 256, 2), dim3(256), 0, stream>>>(h, W2, b2, recon);
  k_rot<<<dim3(NV / 16), dim3(256), 0, stream>>>(
      xyz, recon, wmat, area, nbrs, nnbr, Rbuf, out);
  k_scatter<<<dim3(NV * 16 / 256), dim3(256), 0, stream>>>(
      xyz, recon, wmat, area, Rbuf, rcount, rlist, grecon);
  k_mlp2_bwd<<<dim3(118, 8), dim3(256), 0, stream>>>(grecon, W2, gh);
  k_mlp1_bwd<<<dim3(B_, 8), dim3(256), 0, stream>>>(gh, h, W1, out + B_);
}

// Round 3
// 775.385 us; speedup vs baseline: 1.4977x; 1.2464x over previous
//
#include <hip/hip_runtime.h>

// Problem constants (from reference)
constexpr int B_ = 16;
constexpr int NV = 20000;      // N vertices
constexpr int KN = 16;         // K neighbors
constexpr int LAT = 256;       // LATENT
constexpr int HID = 1024;      // HIDDEN
constexpr int N3 = 60000;      // N*3
constexpr int RCAP = 64;       // reverse-adjacency capacity
constexpr float INV_NK = 1.0f / (20000.0f * 16.0f);

// Workspace layout (float units)
constexpr size_t H_OFF      = 0;                          // h        [16][1024]
constexpr size_t RECON_OFF  = H_OFF + B_ * HID;           // recon    [16][60000]
constexpr size_t GRECON_OFF = RECON_OFF + B_ * N3;        // g_recon  [16][60000]
constexpr size_t GH_OFF     = GRECON_OFF + B_ * N3;       // g_h      [16][1024]
constexpr size_t RBUF_OFF   = GH_OFF + B_ * HID;          // R+ownG   [20000][16][12]
constexpr size_t RCOUNT_OFF = RBUF_OFF + (size_t)NV * 16 * 12;  // int [20000]
constexpr size_t RLIST_OFF  = RCOUNT_OFF + NV;            // int     [20000][64]

__device__ __forceinline__ void atomAddF(float* p, float v) {
  unsafeAtomicAdd(p, v);   // hardware global_atomic_add_f32 on gfx950
}

// ---------------- h = relu(code @ W1 + b1) ----------------
__global__ __launch_bounds__(256) void k_mlp1(
    const float* __restrict__ code, const float* __restrict__ W1,
    const float* __restrict__ b1, float* __restrict__ h) {
  int t = blockIdx.x * 256 + threadIdx.x;     // 0..16383
  int b = t >> 10, hd = t & 1023;
  const float* c = code + b * LAT;
  float acc = b1[hd];
  #pragma unroll 4
  for (int l = 0; l < LAT; ++l) acc += c[l] * W1[l * HID + hd];
  h[t] = fmaxf(acc, 0.0f);
}

// ---------------- recon = h @ W2 + b2 ----------------
// grid (59 j-tiles of 1024, 8 hd-chunks of 128). Thread owns 4 j (float4),
// all 16 b in registers. W2 streamed as dwordx4; h chunk in LDS (broadcast b128).
__global__ __launch_bounds__(256) void k_mlp2(
    const float* __restrict__ h, const float* __restrict__ W2,
    const float* __restrict__ b2, float* __restrict__ recon) {
  __shared__ float hs[16][128];
  const int tid = threadIdx.x;
  const int hd0 = blockIdx.y * 128;
  #pragma unroll
  for (int r = 0; r < 8; ++r) {               // stage h[0:16][hd0:hd0+128]
    int idx = r * 256 + tid;
    int bb = idx >> 7, cc = idx & 127;
    hs[bb][cc] = h[bb * HID + hd0 + cc];      // coalesced, conflict-free
  }
  __syncthreads();

  const int j4 = blockIdx.x * 1024 + tid * 4;
  if (j4 >= N3) return;                        // no further barriers

  float4 acc[16];
  #pragma unroll
  for (int b = 0; b < 16; ++b) acc[b] = make_float4(0.f, 0.f, 0.f, 0.f);

  const float* wp = W2 + (size_t)hd0 * N3 + j4;
  for (int i = 0; i < 128; i += 4) {
    float4 w0 = *(const float4*)(wp);
    float4 w1 = *(const float4*)(wp + (size_t)N3);
    float4 w2 = *(const float4*)(wp + (size_t)2 * N3);
    float4 w3 = *(const float4*)(wp + (size_t)3 * N3);
    wp += (size_t)4 * N3;
    #pragma unroll
    for (int b = 0; b < 16; ++b) {
      float4 hb = *(const float4*)&hs[b][i];   // broadcast ds_read_b128
      acc[b].x += hb.x * w0.x + hb.y * w1.x + hb.z * w2.x + hb.w * w3.x;
      acc[b].y += hb.x * w0.y + hb.y * w1.y + hb.z * w2.y + hb.w * w3.y;
      acc[b].z += hb.x * w0.z + hb.y * w1.z + hb.z * w2.z + hb.w * w3.z;
      acc[b].w += hb.x * w0.w + hb.y * w1.w + hb.z * w2.w + hb.w * w3.w;
    }
  }

  float4 bias = make_float4(0.f, 0.f, 0.f, 0.f);
  if (blockIdx.y == 0) bias = *(const float4*)(b2 + j4);
  #pragma unroll
  for (int b = 0; b < 16; ++b) {
    float* rp = recon + (size_t)b * N3 + j4;
    atomAddF(rp + 0, acc[b].x + bias.x);
    atomAddF(rp + 1, acc[b].y + bias.y);
    atomAddF(rp + 2, acc[b].z + bias.z);
    atomAddF(rp + 3, acc[b].w + bias.w);
  }
}

// ---------------- reverse adjacency fill ----------------
__global__ __launch_bounds__(256) void k_fill(
    const int* __restrict__ nbrs, const int* __restrict__ nnbr,
    int* __restrict__ rcount, int* __restrict__ rlist) {
  int e = blockIdx.x * 256 + threadIdx.x;   // 0..319999
  int n = e >> 4, k = e & 15;
  if (k < nnbr[n]) {
    int v = nbrs[e];
    int slot = atomicAdd(&rcount[v], 1);
    if (slot < RCAP) rlist[v * RCAP + slot] = e;
  }
}

// ---------------- per-vertex: S, Jacobi->R, energy, own-grad ----------------
__global__ __launch_bounds__(256) void k_rot(
    const float* __restrict__ xyz, const float* __restrict__ recon,
    const float* __restrict__ wmat, const float* __restrict__ area,
    const int* __restrict__ nbrs, const int* __restrict__ nnbr,
    float* __restrict__ Rbuf, float* __restrict__ energy) {
  __shared__ float red[64];
  const int tid = threadIdx.x;
  const int b = tid & 15, nl = tid >> 4;
  const int n = blockIdx.x * 16 + nl;       // grid 1250 -> exactly 20000
  const float* xb = xyz + b * N3;
  const float* qb = recon + b * N3;
  const int nn = nnbr[n];
  const float ar = area[n];
  const float x0 = xb[n*3+0], x1 = xb[n*3+1], x2 = xb[n*3+2];
  const float q0 = qb[n*3+0], q1 = qb[n*3+1], q2 = qb[n*3+2];

  float S00=0,S01=0,S02=0,S10=0,S11=0,S12=0,S20=0,S21=0,S22=0;
  for (int k = 0; k < nn; ++k) {
    int m = nbrs[n * KN + k];
    float w = wmat[n * KN + k];
    float dx = x0 - xb[m*3+0], dy = x1 - xb[m*3+1], dz = x2 - xb[m*3+2];
    float ex = q0 - qb[m*3+0], ey = q1 - qb[m*3+1], ez = q2 - qb[m*3+2];
    S00 += w*dx*ex; S01 += w*dx*ey; S02 += w*dx*ez;
    S10 += w*dy*ex; S11 += w*dy*ey; S12 += w*dy*ez;
    S20 += w*dz*ex; S21 += w*dz*ey; S22 += w*dz*ez;
  }

  float A00 = S00*S00 + S10*S10 + S20*S20;
  float A01 = S00*S01 + S10*S11 + S20*S21;
  float A02 = S00*S02 + S10*S12 + S20*S22;
  float A11 = S01*S01 + S11*S11 + S21*S21;
  float A12 = S01*S02 + S11*S12 + S21*S22;
  float A22 = S02*S02 + S12*S12 + S22*S22;
  float V00=1,V01=0,V02=0, V10=0,V11=1,V12=0, V20=0,V21=0,V22=1;

  auto rot = [&](float& app, float& aqq, float& apq, float& arp, float& arq,
                 float& vp0, float& vp1, float& vp2,
                 float& vq0, float& vq1, float& vq2) {
    float a = apq;
    if (fabsf(a) > 1e-37f) {
      float tau = (aqq - app) * 0.5f / a;
      float t = copysignf(1.0f, tau) / (fabsf(tau) + sqrtf(1.0f + tau * tau));
      float c = rsqrtf(1.0f + t * t);
      float s = t * c;
      float napp = c*c*app - 2.0f*s*c*a + s*s*aqq;
      float naqq = s*s*app + 2.0f*s*c*a + c*c*aqq;
      app = napp; aqq = naqq; apq = 0.0f;
      float rp = arp, rq = arq;
      arp = c*rp - s*rq; arq = s*rp + c*rq;
      float t0, t1;
      t0=vp0; t1=vq0; vp0 = c*t0 - s*t1; vq0 = s*t0 + c*t1;
      t0=vp1; t1=vq1; vp1 = c*t0 - s*t1; vq1 = s*t0 + c*t1;
      t0=vp2; t1=vq2; vp2 = c*t0 - s*t1; vq2 = s*t0 + c*t1;
    }
  };
  #pragma unroll
  for (int sweep = 0; sweep < 6; ++sweep) {
    rot(A00,A11,A01, A02,A12, V00,V10,V20, V01,V11,V21);
    rot(A00,A22,A02, A01,A12, V00,V10,V20, V02,V12,V22);
    rot(A11,A22,A12, A01,A02, V01,V11,V21, V02,V12,V22);
  }
  auto sw = [](float& a, float& c) { float t = a; a = c; c = t; };
  if (A00 < A11) { sw(A00,A11); sw(V00,V01); sw(V10,V11); sw(V20,V21); }
  if (A00 < A22) { sw(A00,A22); sw(V00,V02); sw(V10,V12); sw(V20,V22); }
  if (A11 < A22) { sw(A11,A22); sw(V01,V02); sw(V11,V12); sw(V21,V22); }

  float v1x=V00, v1y=V10, v1z=V20;
  float v2x=V01, v2y=V11, v2z=V21;

  float u1x = S00*v1x + S01*v1y + S02*v1z;
  float u1y = S10*v1x + S11*v1y + S12*v1z;
  float u1z = S20*v1x + S21*v1y + S22*v1z;
  float s1sq = u1x*u1x + u1y*u1y + u1z*u1z;
  if (s1sq > 1e-30f) { float r = rsqrtf(s1sq); u1x*=r; u1y*=r; u1z*=r; }
  else { u1x = 1.0f; u1y = 0.0f; u1z = 0.0f; }

  float u2x = S00*v2x + S01*v2y + S02*v2z;
  float u2y = S10*v2x + S11*v2y + S12*v2z;
  float u2z = S20*v2x + S21*v2y + S22*v2z;
  float pr = u2x*u1x + u2y*u1y + u2z*u1z;
  u2x -= pr*u1x; u2y -= pr*u1y; u2z -= pr*u1z;
  float s2sq = u2x*u2x + u2y*u2y + u2z*u2z;
  if (s2sq > 1e-12f * s1sq + 1e-30f) {
    float r = rsqrtf(s2sq); u2x*=r; u2y*=r; u2z*=r;
  } else {
    float ex_ = (fabsf(u1x) < 0.9f) ? 1.0f : 0.0f;
    float ey_ = 1.0f - ex_;
    float pp = ex_*u1x + ey_*u1y;
    u2x = ex_ - pp*u1x; u2y = ey_ - pp*u1y; u2z = -pp*u1z;
    float r = rsqrtf(u2x*u2x + u2y*u2y + u2z*u2z);
    u2x*=r; u2y*=r; u2z*=r;
  }
  float u3x = u1y*u2z - u1z*u2y, u3y = u1z*u2x - u1x*u2z, u3z = u1x*u2y - u1y*u2x;
  float v3x = v1y*v2z - v1z*v2y, v3y = v1z*v2x - v1x*v2z, v3z = v1x*v2y - v1y*v2x;

  float R00 = v1x*u1x + v2x*u2x + v3x*u3x;
  float R01 = v1x*u1y + v2x*u2y + v3x*u3y;
  float R02 = v1x*u1z + v2x*u2z + v3x*u3z;
  float R10 = v1y*u1x + v2y*u2x + v3y*u3x;
  float R11 = v1y*u1y + v2y*u2y + v3y*u3y;
  float R12 = v1y*u1z + v2y*u2z + v3y*u3z;
  float R20 = v1z*u1x + v2z*u2x + v3z*u3x;
  float R21 = v1z*u1y + v2z*u2y + v3z*u3y;
  float R22 = v1z*u1z + v2z*u2z + v3z*u3z;

  float esum = 0, go0 = 0, go1 = 0, go2 = 0;
  const float gf = 2.0f * ar * INV_NK;
  for (int k = 0; k < nn; ++k) {
    int m = nbrs[n * KN + k];
    float w = wmat[n * KN + k];
    float dx = x0 - xb[m*3+0], dy = x1 - xb[m*3+1], dz = x2 - xb[m*3+2];
    float ex = q0 - qb[m*3+0], ey = q1 - qb[m*3+1], ez = q2 - qb[m*3+2];
    float rx = ex - (R00*dx + R01*dy + R02*dz);
    float ry = ey - (R10*dx + R11*dy + R12*dz);
    float rz = ez - (R20*dx + R21*dy + R22*dz);
    esum += w * (rx*rx + ry*ry + rz*rz);
    float gc = gf * w;
    go0 += gc*rx; go1 += gc*ry; go2 += gc*rz;
  }
  esum *= ar * INV_NK;

  float4* rp = (float4*)(Rbuf + (size_t)(n * 16 + b) * 12);
  rp[0] = make_float4(R00, R01, R02, R10);
  rp[1] = make_float4(R11, R12, R20, R21);
  rp[2] = make_float4(R22, go0, go1, go2);

  esum += __shfl_down(esum, 32);
  esum += __shfl_down(esum, 16);
  int wave = tid >> 6, lane = tid & 63;
  if (lane < 16) red[wave * 16 + lane] = esum;
  __syncthreads();
  if (tid < 16) atomAddF(&energy[tid], red[tid] + red[16 + tid] + red[32 + tid] + red[48 + tid]);
}

// ---------------- gather incoming edge grads, final g_recon (no atomics) ----------------
__global__ __launch_bounds__(256) void k_scatter(
    const float* __restrict__ xyz, const float* __restrict__ recon,
    const float* __restrict__ wmat, const float* __restrict__ area,
    const float* __restrict__ Rbuf, const int* __restrict__ rcount,
    const int* __restrict__ rlist, float* __restrict__ grecon) {
  int t = blockIdx.x * 256 + threadIdx.x;   // 20000*16 threads
  int v = t >> 4, b = t & 15;
  const float* xb = xyz + b * N3;
  const float* qb = recon + b * N3;
  const float xv0 = xb[v*3+0], xv1 = xb[v*3+1], xv2 = xb[v*3+2];
  const float qv0 = qb[v*3+0], qv1 = qb[v*3+1], qv2 = qb[v*3+2];
  float g0 = 0, g1 = 0, g2 = 0;
  int deg = min(rcount[v], RCAP);
  for (int i = 0; i < deg; ++i) {
    int e = rlist[v * RCAP + i];
    int n = e >> 4;
    float gc = 2.0f * INV_NK * area[n] * wmat[e];
    const float4* rp = (const float4*)(Rbuf + (size_t)(n * 16 + b) * 12);
    float4 ra = rp[0], rb = rp[1], rc = rp[2];
    float dx = xb[n*3+0] - xv0, dy = xb[n*3+1] - xv1, dz = xb[n*3+2] - xv2;
    float ex = qb[n*3+0] - qv0, ey = qb[n*3+1] - qv1, ez = qb[n*3+2] - qv2;
    float rx = ex - (ra.x*dx + ra.y*dy + ra.z*dz);
    float ry = ey - (ra.w*dx + rb.x*dy + rb.y*dz);
    float rz = ez - (rb.z*dx + rb.w*dy + rc.x*dz);
    g0 -= gc*rx; g1 -= gc*ry; g2 -= gc*rz;
  }
  const float4* op = (const float4*)(Rbuf + (size_t)(v * 16 + b) * 12);
  float4 oc = op[2];
  g0 += oc.y; g1 += oc.z; g2 += oc.w;
  float* gq = grecon + (size_t)b * N3 + v * 3;
  gq[0] = g0; gq[1] = g1; gq[2] = g2;
}

// ---------------- g_h = g_recon @ W2^T -------------
// No LDS. Lanes: 16 along j (float4) x 4 row-groups; 2 rows per lane-group.
// Block = 4 waves x 8 rows = 32 rows; grid (16 j-phases, 32 row-tiles).
// W2 rows read coalesced dwordx4; gr broadcast from L1/L2 (3.84 MB resident).
__global__ __launch_bounds__(256, 2) void k_mlp2_bwd(
    const float* __restrict__ gr, const float* __restrict__ W2,
    float* __restrict__ gh) {
  const int tid = threadIdx.x;
  const int lane = tid & 63;
  const int wv = tid >> 6;
  const int laneJ = lane & 15, laneR = lane >> 4;
  const int row0 = blockIdx.y * 32 + wv * 8 + laneR * 2;   // rows row0, row0+1

  float4 acc0[16], acc1[16];
  #pragma unroll
  for (int b = 0; b < 16; ++b) {
    acc0[b] = make_float4(0.f, 0.f, 0.f, 0.f);
    acc1[b] = make_float4(0.f, 0.f, 0.f, 0.f);
  }

  const int jbase = blockIdx.x * 64 + laneJ * 4;
  const float* w2r0 = W2 + (size_t)row0 * N3;
  const float* w2r1 = W2 + (size_t)(row0 + 1) * N3;

  for (int it = 0; it < 59; ++it) {
    int j = jbase + it * 1024;
    if (j < N3) {
      float4 w0 = *(const float4*)(w2r0 + j);
      float4 w1 = *(const float4*)(w2r1 + j);
      #pragma unroll
      for (int b = 0; b < 16; ++b) {
        float4 g = *(const float4*)(gr + (size_t)b * N3 + j);
        acc0[b].x += g.x * w0.x; acc0[b].y += g.y * w0.y;
        acc0[b].z += g.z * w0.z; acc0[b].w += g.w * w0.w;
        acc1[b].x += g.x * w1.x; acc1[b].y += g.y * w1.y;
        acc1[b].z += g.z * w1.z; acc1[b].w += g.w * w1.w;
      }
    }
  }

  // fold j-components, then reduce across the 16 j-lanes (DPP shfl_xor)
  float s0[16], s1[16];
  #pragma unroll
  for (int b = 0; b < 16; ++b) {
    s0[b] = (acc0[b].x + acc0[b].y) + (acc0[b].z + acc0[b].w);
    s1[b] = (acc1[b].x + acc1[b].y) + (acc1[b].z + acc1[b].w);
  }
  #pragma unroll
  for (int m = 1; m <= 8; m <<= 1) {
    #pragma unroll
    for (int b = 0; b < 16; ++b) {
      s0[b] += __shfl_xor(s0[b], m);
      s1[b] += __shfl_xor(s1[b], m);
    }
  }
  if (laneJ == 0) {
    #pragma unroll
    for (int b = 0; b < 16; ++b) {
      atomAddF(&gh[b * HID + row0], s0[b]);
      atomAddF(&gh[b * HID + row0 + 1], s1[b]);
    }
  }
}

// ---------------- g_code = (g_h * relu') @ W1^T ----------------
__global__ __launch_bounds__(256) void k_mlp1_bwd(
    const float* __restrict__ gh, const float* __restrict__ h,
    const float* __restrict__ W1, float* __restrict__ gcode) {
  __shared__ float gm[128];
  const int b = blockIdx.x;
  const int hd0 = blockIdx.y * 128;
  const int l = threadIdx.x;
  if (l < 128) {
    float g = gh[b * HID + hd0 + l];
    gm[l] = (h[b * HID + hd0 + l] > 0.0f) ? g : 0.0f;
  }
  __syncthreads();
  const float4* wp = (const float4*)(W1 + (size_t)l * HID + hd0);
  float acc = 0.0f;
  #pragma unroll
  for (int i = 0; i < 32; ++i) {
    float4 w4 = wp[i];
    acc += w4.x * gm[i*4+0] + w4.y * gm[i*4+1] + w4.z * gm[i*4+2] + w4.w * gm[i*4+3];
  }
  atomAddF(&gcode[b * LAT + l], acc);
}

extern "C" void kernel_launch(void* const* d_in, const int* in_sizes, int n_in,
                              void* d_out, int out_size, void* d_ws, size_t ws_size,
                              hipStream_t stream) {
  const float* code = (const float*)d_in[0];
  const float* W1   = (const float*)d_in[1];
  const float* b1   = (const float*)d_in[2];
  const float* W2   = (const float*)d_in[3];
  const float* b2   = (const float*)d_in[4];
  const float* xyz  = (const float*)d_in[5];
  const float* wmat = (const float*)d_in[6];
  const float* area = (const float*)d_in[7];
  const int* nbrs   = (const int*)d_in[8];
  const int* nnbr   = (const int*)d_in[9];

  float* out = (float*)d_out;           // [16] meanEnergy, [16*256] code_grad
  float* ws = (float*)d_ws;
  float* h      = ws + H_OFF;
  float* recon  = ws + RECON_OFF;
  float* grecon = ws + GRECON_OFF;
  float* gh     = ws + GH_OFF;
  float* Rbuf   = ws + RBUF_OFF;
  int*   rcount = (int*)(ws + RCOUNT_OFF);
  int*   rlist  = (int*)(ws + RLIST_OFF);

  hipMemsetAsync(recon, 0, (size_t)B_ * N3 * sizeof(float), stream);
  hipMemsetAsync(gh, 0, (size_t)B_ * HID * sizeof(float), stream);
  hipMemsetAsync(rcount, 0, (size_t)NV * sizeof(int), stream);
  hipMemsetAsync(out, 0, (size_t)(B_ + B_ * LAT) * sizeof(float), stream);

  k_fill<<<dim3(NV * KN / 256), dim3(256), 0, stream>>>(nbrs, nnbr, rcount, rlist);
  k_mlp1<<<dim3(64), dim3(256), 0, stream>>>(code, W1, b1, h);
  k_mlp2<<<dim3(59, 8), dim3(256), 0, stream>>>(h, W2, b2, recon);
  k_rot<<<dim3(NV / 16), dim3(256), 0, stream>>>(
      xyz, recon, wmat, area, nbrs, nnbr, Rbuf, out);
  k_scatter<<<dim3(NV * 16 / 256), dim3(256), 0, stream>>>(
      xyz, recon, wmat, area, Rbuf, rcount, rlist, grecon);
  k_mlp2_bwd<<<dim3(16, 32), dim3(256), 0, stream>>>(grecon, W2, gh);
  k_mlp1_bwd<<<dim3(B_, 8), dim3(256), 0, stream>>>(gh, h, W1, out + B_);
}

// Round 4
// 597.544 us; speedup vs baseline: 1.9434x; 1.2976x over previous
//
#include <hip/hip_runtime.h>

// Problem constants (from reference)
constexpr int B_ = 16;
constexpr int NV = 20000;      // N vertices
constexpr int KN = 16;         // K neighbors
constexpr int LAT = 256;       // LATENT
constexpr int HID = 1024;      // HIDDEN
constexpr int N3 = 60000;      // N*3
constexpr int RCAP = 64;       // reverse-adjacency capacity
constexpr int NCHUNK = 8;      // K-split for mlp2 (1024/128)
constexpr float INV_NK = 1.0f / (20000.0f * 16.0f);

// Workspace layout (float units)
constexpr size_t H_OFF      = 0;                           // h        [16][1024]
constexpr size_t XYZT_OFF   = H_OFF + B_ * HID;            // xyzT     [60000][16]
constexpr size_t RECONT_OFF = XYZT_OFF + (size_t)N3 * 16;  // reconT   [60000][16]
constexpr size_t GRECON_OFF = RECONT_OFF + (size_t)N3 * 16;// g_recon  [16][60000]
constexpr size_t GH_OFF     = GRECON_OFF + (size_t)B_ * N3;// g_h      [16][1024]
constexpr size_t RBUF_OFF   = GH_OFF + B_ * HID;           // R+ownG   [20000][12][16]
constexpr size_t RCOUNT_OFF = RBUF_OFF + (size_t)NV * 12 * 16;  // int [20000]
constexpr size_t RLIST_OFF  = RCOUNT_OFF + NV;             // int     [20000][64]
constexpr size_t PART_OFF   = RLIST_OFF + (size_t)NV * RCAP;    // [8][60000][16]

__device__ __forceinline__ void atomAddF(float* p, float v) {
  unsafeAtomicAdd(p, v);   // hardware global_atomic_add_f32 on gfx950
}

// ---------------- h = relu(code @ W1 + b1) ----------------
__global__ __launch_bounds__(256) void k_mlp1(
    const float* __restrict__ code, const float* __restrict__ W1,
    const float* __restrict__ b1, float* __restrict__ h) {
  int t = blockIdx.x * 256 + threadIdx.x;     // 0..16383
  int b = t >> 10, hd = t & 1023;
  const float* c = code + b * LAT;
  float acc = b1[hd];
  #pragma unroll 4
  for (int l = 0; l < LAT; ++l) acc += c[l] * W1[l * HID + hd];
  h[t] = fmaxf(acc, 0.0f);
}

// ---------------- xyzT[n3][16] = transpose(xyz[16][n3]) via LDS tile ----------------
__global__ __launch_bounds__(256) void k_xpose(
    const float* __restrict__ xyz, float* __restrict__ xyzT) {
  __shared__ float sm[64][17];
  const int tid = threadIdx.x;
  const int n30 = blockIdx.x * 64;
  {
    const int n3l = tid & 63, bq = tid >> 6;      // 4 b per pass
    #pragma unroll
    for (int p = 0; p < 4; ++p) {
      int b = p * 4 + bq;
      if (n30 + n3l < N3) sm[n3l][b] = xyz[(size_t)b * N3 + n30 + n3l];
    }
  }
  __syncthreads();
  {
    const int b = tid & 15, nq = tid >> 4;        // 16 n3l per pass
    #pragma unroll
    for (int p = 0; p < 4; ++p) {
      int n3l = p * 16 + nq;
      if (n30 + n3l < N3) xyzT[(size_t)(n30 + n3l) * 16 + b] = sm[n3l][b];
    }
  }
}

// ---------------- recon partials: part[chunk][j][b] = h-chunk @ W2-chunk ----------------
// grid (59 j-tiles, 8 K-chunks of 128). Thread owns 4 j, all 16 b.
// Software-pipelined: next 4 W2 rows prefetched under current 256 FMAs. No atomics.
__global__ __launch_bounds__(256) void k_mlp2(
    const float* __restrict__ h, const float* __restrict__ W2,
    float* __restrict__ part) {
  __shared__ float hs[16][128];
  const int tid = threadIdx.x;
  const int hd0 = blockIdx.y * 128;
  #pragma unroll
  for (int r = 0; r < 8; ++r) {               // stage h[0:16][hd0:hd0+128]
    int idx = r * 256 + tid;
    int bb = idx >> 7, cc = idx & 127;
    hs[bb][cc] = h[bb * HID + hd0 + cc];
  }
  __syncthreads();

  const int j4 = blockIdx.x * 1024 + tid * 4;
  if (j4 >= N3) return;

  float4 acc[16];
  #pragma unroll
  for (int b = 0; b < 16; ++b) acc[b] = make_float4(0.f, 0.f, 0.f, 0.f);

  const float* wp = W2 + (size_t)hd0 * N3 + j4;
  float4 w0 = *(const float4*)(wp);
  float4 w1 = *(const float4*)(wp + (size_t)N3);
  float4 w2 = *(const float4*)(wp + (size_t)2 * N3);
  float4 w3 = *(const float4*)(wp + (size_t)3 * N3);

  for (int g = 0; g < 32; ++g) {
    const float* np = wp + (size_t)4 * N3;
    float4 n0, n1, n2, n3;
    if (g < 31) {                             // prefetch next 4 rows
      n0 = *(const float4*)(np);
      n1 = *(const float4*)(np + (size_t)N3);
      n2 = *(const float4*)(np + (size_t)2 * N3);
      n3 = *(const float4*)(np + (size_t)3 * N3);
    }
    #pragma unroll
    for (int b = 0; b < 16; ++b) {
      float4 hb = *(const float4*)&hs[b][g * 4];   // broadcast ds_read_b128
      acc[b].x += hb.x * w0.x + hb.y * w1.x + hb.z * w2.x + hb.w * w3.x;
      acc[b].y += hb.x * w0.y + hb.y * w1.y + hb.z * w2.y + hb.w * w3.y;
      acc[b].z += hb.x * w0.z + hb.y * w1.z + hb.z * w2.z + hb.w * w3.z;
      acc[b].w += hb.x * w0.w + hb.y * w1.w + hb.z * w2.w + hb.w * w3.w;
    }
    wp = np; w0 = n0; w1 = n1; w2 = n2; w3 = n3;
  }

  // store 256B contiguous per thread: part[chunk][j4+jj][b]
  float ac[4][16];
  #pragma unroll
  for (int b = 0; b < 16; ++b) {
    ac[0][b] = acc[b].x; ac[1][b] = acc[b].y;
    ac[2][b] = acc[b].z; ac[3][b] = acc[b].w;
  }
  float* pbase = part + ((size_t)blockIdx.y * N3 + j4) * 16;
  #pragma unroll
  for (int jj = 0; jj < 4; ++jj)
    #pragma unroll
    for (int q = 0; q < 4; ++q)
      *(float4*)(pbase + jj * 16 + q * 4) = make_float4(
          ac[jj][q*4+0], ac[jj][q*4+1], ac[jj][q*4+2], ac[jj][q*4+3]);
}

// ---------------- reconT[j][b] = sum_c part[c][j][b] + b2[j] ----------------
__global__ __launch_bounds__(256) void k_reduce(
    const float* __restrict__ part, const float* __restrict__ b2,
    float* __restrict__ reconT) {
  int t = blockIdx.x * 256 + threadIdx.x;     // one float4 each
  if (t >= N3 * 16 / 4) return;
  size_t pos = (size_t)t * 4;
  int j = t >> 2;
  float4 s = *(const float4*)(part + pos);
  #pragma unroll
  for (int c = 1; c < NCHUNK; ++c) {
    float4 p = *(const float4*)(part + (size_t)c * N3 * 16 + pos);
    s.x += p.x; s.y += p.y; s.z += p.z; s.w += p.w;
  }
  float bias = b2[j];
  s.x += bias; s.y += bias; s.z += bias; s.w += bias;
  *(float4*)(reconT + pos) = s;
}

// ---------------- reverse adjacency fill ----------------
__global__ __launch_bounds__(256) void k_fill(
    const int* __restrict__ nbrs, const int* __restrict__ nnbr,
    int* __restrict__ rcount, int* __restrict__ rlist) {
  int e = blockIdx.x * 256 + threadIdx.x;   // 0..319999
  int n = e >> 4, k = e & 15;
  if (k < nnbr[n]) {
    int v = nbrs[e];
    int slot = atomicAdd(&rcount[v], 1);
    if (slot < RCAP) rlist[v * RCAP + slot] = e;
  }
}

// ---------------- per-vertex: S, Jacobi->R, energy, own-grad (single gather pass) ----------------
// b = tid&15 lane-fastest; xyzT/reconT give 1 cache line per (vertex,coord) per 16 lanes.
__global__ __launch_bounds__(256, 2) void k_rot(
    const float* __restrict__ xT, const float* __restrict__ qT,
    const float* __restrict__ wmat, const float* __restrict__ area,
    const int* __restrict__ nbrs, const int* __restrict__ nnbr,
    float* __restrict__ Rbuf, float* __restrict__ energy) {
  __shared__ float red[64];
  const int tid = threadIdx.x;
  const int b = tid & 15, nl = tid >> 4;
  const int n = blockIdx.x * 16 + nl;       // grid 1250 -> exactly 20000
  const int nn = nnbr[n];
  const float ar = area[n];
  const float x0 = xT[(size_t)n*48 + b],      x1 = xT[(size_t)n*48 + 16 + b],
              x2 = xT[(size_t)n*48 + 32 + b];
  const float q0 = qT[(size_t)n*48 + b],      q1 = qT[(size_t)n*48 + 16 + b],
              q2 = qT[(size_t)n*48 + 32 + b];

  float dX[KN], dY[KN], dZ[KN], eX[KN], eY[KN], eZ[KN], wk[KN];
  float S00=0,S01=0,S02=0,S10=0,S11=0,S12=0,S20=0,S21=0,S22=0;
  #pragma unroll
  for (int k = 0; k < KN; ++k) {
    float w=0, dx=0, dy=0, dz=0, ex=0, ey=0, ez=0;
    if (k < nn) {
      int m = nbrs[n * KN + k];             // broadcast across 16 b-lanes
      w = wmat[n * KN + k];
      size_t mb = (size_t)m * 48 + b;
      dx = x0 - xT[mb]; dy = x1 - xT[mb + 16]; dz = x2 - xT[mb + 32];
      ex = q0 - qT[mb]; ey = q1 - qT[mb + 16]; ez = q2 - qT[mb + 32];
    }
    wk[k]=w; dX[k]=dx; dY[k]=dy; dZ[k]=dz; eX[k]=ex; eY[k]=ey; eZ[k]=ez;
    S00 += w*dx*ex; S01 += w*dx*ey; S02 += w*dx*ez;
    S10 += w*dy*ex; S11 += w*dy*ey; S12 += w*dy*ez;
    S20 += w*dz*ex; S21 += w*dz*ey; S22 += w*dz*ez;
  }

  float A00 = S00*S00 + S10*S10 + S20*S20;
  float A01 = S00*S01 + S10*S11 + S20*S21;
  float A02 = S00*S02 + S10*S12 + S20*S22;
  float A11 = S01*S01 + S11*S11 + S21*S21;
  float A12 = S01*S02 + S11*S12 + S21*S22;
  float A22 = S02*S02 + S12*S12 + S22*S22;
  float V00=1,V01=0,V02=0, V10=0,V11=1,V12=0, V20=0,V21=0,V22=1;

  auto rot = [&](float& app, float& aqq, float& apq, float& arp, float& arq,
                 float& vp0, float& vp1, float& vp2,
                 float& vq0, float& vq1, float& vq2) {
    float a = apq;
    if (fabsf(a) > 1e-37f) {
      float tau = (aqq - app) * 0.5f / a;
      float t = copysignf(1.0f, tau) / (fabsf(tau) + sqrtf(1.0f + tau * tau));
      float c = rsqrtf(1.0f + t * t);
      float s = t * c;
      float napp = c*c*app - 2.0f*s*c*a + s*s*aqq;
      float naqq = s*s*app + 2.0f*s*c*a + c*c*aqq;
      app = napp; aqq = naqq; apq = 0.0f;
      float rp = arp, rq = arq;
      arp = c*rp - s*rq; arq = s*rp + c*rq;
      float t0, t1;
      t0=vp0; t1=vq0; vp0 = c*t0 - s*t1; vq0 = s*t0 + c*t1;
      t0=vp1; t1=vq1; vp1 = c*t0 - s*t1; vq1 = s*t0 + c*t1;
      t0=vp2; t1=vq2; vp2 = c*t0 - s*t1; vq2 = s*t0 + c*t1;
    }
  };
  #pragma unroll
  for (int sweep = 0; sweep < 6; ++sweep) {
    rot(A00,A11,A01, A02,A12, V00,V10,V20, V01,V11,V21);
    rot(A00,A22,A02, A01,A12, V00,V10,V20, V02,V12,V22);
    rot(A11,A22,A12, A01,A02, V01,V11,V21, V02,V12,V22);
  }
  auto sw = [](float& a, float& c) { float t = a; a = c; c = t; };
  if (A00 < A11) { sw(A00,A11); sw(V00,V01); sw(V10,V11); sw(V20,V21); }
  if (A00 < A22) { sw(A00,A22); sw(V00,V02); sw(V10,V12); sw(V20,V22); }
  if (A11 < A22) { sw(A11,A22); sw(V01,V02); sw(V11,V12); sw(V21,V22); }

  float v1x=V00, v1y=V10, v1z=V20;
  float v2x=V01, v2y=V11, v2z=V21;

  float u1x = S00*v1x + S01*v1y + S02*v1z;
  float u1y = S10*v1x + S11*v1y + S12*v1z;
  float u1z = S20*v1x + S21*v1y + S22*v1z;
  float s1sq = u1x*u1x + u1y*u1y + u1z*u1z;
  if (s1sq > 1e-30f) { float r = rsqrtf(s1sq); u1x*=r; u1y*=r; u1z*=r; }
  else { u1x = 1.0f; u1y = 0.0f; u1z = 0.0f; }

  float u2x = S00*v2x + S01*v2y + S02*v2z;
  float u2y = S10*v2x + S11*v2y + S12*v2z;
  float u2z = S20*v2x + S21*v2y + S22*v2z;
  float pr = u2x*u1x + u2y*u1y + u2z*u1z;
  u2x -= pr*u1x; u2y -= pr*u1y; u2z -= pr*u1z;
  float s2sq = u2x*u2x + u2y*u2y + u2z*u2z;
  if (s2sq > 1e-12f * s1sq + 1e-30f) {
    float r = rsqrtf(s2sq); u2x*=r; u2y*=r; u2z*=r;
  } else {
    float ex_ = (fabsf(u1x) < 0.9f) ? 1.0f : 0.0f;
    float ey_ = 1.0f - ex_;
    float pp = ex_*u1x + ey_*u1y;
    u2x = ex_ - pp*u1x; u2y = ey_ - pp*u1y; u2z = -pp*u1z;
    float r = rsqrtf(u2x*u2x + u2y*u2y + u2z*u2z);
    u2x*=r; u2y*=r; u2z*=r;
  }
  float u3x = u1y*u2z - u1z*u2y, u3y = u1z*u2x - u1x*u2z, u3z = u1x*u2y - u1y*u2x;
  float v3x = v1y*v2z - v1z*v2y, v3y = v1z*v2x - v1x*v2z, v3z = v1x*v2y - v1y*v2x;

  float R00 = v1x*u1x + v2x*u2x + v3x*u3x;
  float R01 = v1x*u1y + v2x*u2y + v3x*u3y;
  float R02 = v1x*u1z + v2x*u2z + v3x*u3z;
  float R10 = v1y*u1x + v2y*u2x + v3y*u3x;
  float R11 = v1y*u1y + v2y*u2y + v3y*u3y;
  float R12 = v1y*u1z + v2y*u2z + v3y*u3z;
  float R20 = v1z*u1x + v2z*u2x + v3z*u3x;
  float R21 = v1z*u1y + v2z*u2y + v3z*u3y;
  float R22 = v1z*u1z + v2z*u2z + v3z*u3z;

  // residuals from registers (no second gather)
  float esum = 0, go0 = 0, go1 = 0, go2 = 0;
  const float gf = 2.0f * ar * INV_NK;
  #pragma unroll
  for (int k = 0; k < KN; ++k) {
    float w = wk[k];
    float dx = dX[k], dy = dY[k], dz = dZ[k];
    float rx = eX[k] - (R00*dx + R01*dy + R02*dz);
    float ry = eY[k] - (R10*dx + R11*dy + R12*dz);
    float rz = eZ[k] - (R20*dx + R21*dy + R22*dz);
    esum += w * (rx*rx + ry*ry + rz*rz);
    float gc = gf * w;
    go0 += gc*rx; go1 += gc*ry; go2 += gc*rz;
  }
  esum *= ar * INV_NK;

  // component-major store: Rbuf[n][12][16] — coalesced for both rot and scatter
  float* rb = Rbuf + (size_t)n * 192 + b;
  rb[0]=R00;  rb[16]=R01;  rb[32]=R02;
  rb[48]=R10; rb[64]=R11;  rb[80]=R12;
  rb[96]=R20; rb[112]=R21; rb[128]=R22;
  rb[144]=go0; rb[160]=go1; rb[176]=go2;

  esum += __shfl_down(esum, 32);
  esum += __shfl_down(esum, 16);
  int wave = tid >> 6, lane = tid & 63;
  if (lane < 16) red[wave * 16 + lane] = esum;
  __syncthreads();
  if (tid < 16) atomAddF(&energy[tid], red[tid] + red[16 + tid] + red[32 + tid] + red[48 + tid]);
}

// ---------------- gather incoming edge grads, final g_recon (no atomics) ----------------
__global__ __launch_bounds__(256) void k_scatter(
    const float* __restrict__ xT, const float* __restrict__ qT,
    const float* __restrict__ wmat, const float* __restrict__ area,
    const float* __restrict__ Rbuf, const int* __restrict__ rcount,
    const int* __restrict__ rlist, float* __restrict__ grecon) {
  int t = blockIdx.x * 256 + threadIdx.x;   // 20000*16 threads
  int v = t >> 4, b = t & 15;
  const float xv0 = xT[(size_t)v*48 + b], xv1 = xT[(size_t)v*48 + 16 + b],
              xv2 = xT[(size_t)v*48 + 32 + b];
  const float qv0 = qT[(size_t)v*48 + b], qv1 = qT[(size_t)v*48 + 16 + b],
              qv2 = qT[(size_t)v*48 + 32 + b];
  float g0 = 0, g1 = 0, g2 = 0;
  int deg = min(rcount[v], RCAP);
  for (int i = 0; i < deg; ++i) {
    int e = rlist[v * RCAP + i];            // broadcast across 16 b-lanes
    int n = e >> 4;
    float gc = 2.0f * INV_NK * area[n] * wmat[e];
    const float* rb = Rbuf + (size_t)n * 192 + b;
    size_t nb = (size_t)n * 48 + b;
    float dx = xT[nb] - xv0, dy = xT[nb+16] - xv1, dz = xT[nb+32] - xv2;
    float ex = qT[nb] - qv0, ey = qT[nb+16] - qv1, ez = qT[nb+32] - qv2;
    float rx = ex - (rb[0]*dx  + rb[16]*dy  + rb[32]*dz);
    float ry = ey - (rb[48]*dx + rb[64]*dy  + rb[80]*dz);
    float rz = ez - (rb[96]*dx + rb[112]*dy + rb[128]*dz);
    g0 -= gc*rx; g1 -= gc*ry; g2 -= gc*rz;
  }
  const float* ob = Rbuf + (size_t)v * 192 + b;
  g0 += ob[144]; g1 += ob[160]; g2 += ob[176];
  float* gq = grecon + (size_t)b * N3 + v * 3;
  gq[0] = g0; gq[1] = g1; gq[2] = g2;
}

// ---------------- g_h = g_recon @ W2^T -------------
__global__ __launch_bounds__(256, 2) void k_mlp2_bwd(
    const float* __restrict__ gr, const float* __restrict__ W2,
    float* __restrict__ gh) {
  const int tid = threadIdx.x;
  const int lane = tid & 63;
  const int wv = tid >> 6;
  const int laneJ = lane & 15, laneR = lane >> 4;
  const int row0 = blockIdx.y * 32 + wv * 8 + laneR * 2;   // rows row0, row0+1

  float4 acc0[16], acc1[16];
  #pragma unroll
  for (int b = 0; b < 16; ++b) {
    acc0[b] = make_float4(0.f, 0.f, 0.f, 0.f);
    acc1[b] = make_float4(0.f, 0.f, 0.f, 0.f);
  }

  const int jbase = blockIdx.x * 64 + laneJ * 4;
  const float* w2r0 = W2 + (size_t)row0 * N3;
  const float* w2r1 = W2 + (size_t)(row0 + 1) * N3;

  for (int it = 0; it < 59; ++it) {
    int j = jbase + it * 1024;
    if (j < N3) {
      float4 w0 = *(const float4*)(w2r0 + j);
      float4 w1 = *(const float4*)(w2r1 + j);
      #pragma unroll
      for (int b = 0; b < 16; ++b) {
        float4 g = *(const float4*)(gr + (size_t)b * N3 + j);
        acc0[b].x += g.x * w0.x; acc0[b].y += g.y * w0.y;
        acc0[b].z += g.z * w0.z; acc0[b].w += g.w * w0.w;
        acc1[b].x += g.x * w1.x; acc1[b].y += g.y * w1.y;
        acc1[b].z += g.z * w1.z; acc1[b].w += g.w * w1.w;
      }
    }
  }

  float s0[16], s1[16];
  #pragma unroll
  for (int b = 0; b < 16; ++b) {
    s0[b] = (acc0[b].x + acc0[b].y) + (acc0[b].z + acc0[b].w);
    s1[b] = (acc1[b].x + acc1[b].y) + (acc1[b].z + acc1[b].w);
  }
  #pragma unroll
  for (int m = 1; m <= 8; m <<= 1) {
    #pragma unroll
    for (int b = 0; b < 16; ++b) {
      s0[b] += __shfl_xor(s0[b], m);
      s1[b] += __shfl_xor(s1[b], m);
    }
  }
  if (laneJ == 0) {
    #pragma unroll
    for (int b = 0; b < 16; ++b) {
      atomAddF(&gh[b * HID + row0], s0[b]);
      atomAddF(&gh[b * HID + row0 + 1], s1[b]);
    }
  }
}

// ---------------- g_code = (g_h * relu') @ W1^T ----------------
__global__ __launch_bounds__(256) void k_mlp1_bwd(
    const float* __restrict__ gh, const float* __restrict__ h,
    const float* __restrict__ W1, float* __restrict__ gcode) {
  __shared__ float gm[128];
  const int b = blockIdx.x;
  const int hd0 = blockIdx.y * 128;
  const int l = threadIdx.x;
  if (l < 128) {
    float g = gh[b * HID + hd0 + l];
    gm[l] = (h[b * HID + hd0 + l] > 0.0f) ? g : 0.0f;
  }
  __syncthreads();
  const float4* wp = (const float4*)(W1 + (size_t)l * HID + hd0);
  float acc = 0.0f;
  #pragma unroll
  for (int i = 0; i < 32; ++i) {
    float4 w4 = wp[i];
    acc += w4.x * gm[i*4+0] + w4.y * gm[i*4+1] + w4.z * gm[i*4+2] + w4.w * gm[i*4+3];
  }
  atomAddF(&gcode[b * LAT + l], acc);
}

extern "C" void kernel_launch(void* const* d_in, const int* in_sizes, int n_in,
                              void* d_out, int out_size, void* d_ws, size_t ws_size,
                              hipStream_t stream) {
  const float* code = (const float*)d_in[0];
  const float* W1   = (const float*)d_in[1];
  const float* b1   = (const float*)d_in[2];
  const float* W2   = (const float*)d_in[3];
  const float* b2   = (const float*)d_in[4];
  const float* xyz  = (const float*)d_in[5];
  const float* wmat = (const float*)d_in[6];
  const float* area = (const float*)d_in[7];
  const int* nbrs   = (const int*)d_in[8];
  const int* nnbr   = (const int*)d_in[9];

  float* out = (float*)d_out;           // [16] meanEnergy, [16*256] code_grad
  float* ws = (float*)d_ws;
  float* h      = ws + H_OFF;
  float* xyzT   = ws + XYZT_OFF;
  float* reconT = ws + RECONT_OFF;
  float* grecon = ws + GRECON_OFF;
  float* gh     = ws + GH_OFF;
  float* Rbuf   = ws + RBUF_OFF;
  int*   rcount = (int*)(ws + RCOUNT_OFF);
  int*   rlist  = (int*)(ws + RLIST_OFF);
  float* part   = ws + PART_OFF;

  // zero only atomic accumulators
  hipMemsetAsync(gh, 0, (size_t)B_ * HID * sizeof(float), stream);
  hipMemsetAsync(rcount, 0, (size_t)NV * sizeof(int), stream);
  hipMemsetAsync(out, 0, (size_t)(B_ + B_ * LAT) * sizeof(float), stream);

  k_fill<<<dim3(NV * KN / 256), dim3(256), 0, stream>>>(nbrs, nnbr, rcount, rlist);
  k_xpose<<<dim3((N3 + 63) / 64), dim3(256), 0, stream>>>(xyz, xyzT);
  k_mlp1<<<dim3(64), dim3(256), 0, stream>>>(code, W1, b1, h);
  k_mlp2<<<dim3(59, NCHUNK), dim3(256), 0, stream>>>(h, W2, part);
  k_reduce<<<dim3((N3 * 16 / 4 + 255) / 256), dim3(256), 0, stream>>>(part, b2, reconT);
  k_rot<<<dim3(NV / 16), dim3(256), 0, stream>>>(
      xyzT, reconT, wmat, area, nbrs, nnbr, Rbuf, out);
  k_scatter<<<dim3(NV * 16 / 256), dim3(256), 0, stream>>>(
      xyzT, reconT, wmat, area, Rbuf, rcount, rlist, grecon);
  k_mlp2_bwd<<<dim3(16, 32), dim3(256), 0, stream>>>(grecon, W2, gh);
  k_mlp1_bwd<<<dim3(B_, 8), dim3(256), 0, stream>>>(gh, h, W1, out + B_);
}